// Round 11
// baseline (60.561 us; speedup 1.0000x reference)
//
#include <hip/hip_runtime.h>

// Problem constants (match reference)
constexpr int Bn = 32;      // batch
constexpr int Nn = 512;     // logical qubits
constexpr int Qq = 512;     // physical qubits
constexpr int Ee = 4096;    // edges per batch
constexpr int CAP = 512;    // edge-bin capacity (expected max ~340)

typedef short bf16x8 __attribute__((ext_vector_type(8)));
typedef float f32x4 __attribute__((ext_vector_type(4)));
typedef unsigned short u16;
typedef unsigned short u16x8 __attribute__((ext_vector_type(8)));
typedef unsigned int u32;

__device__ inline u16 f2bf(float f) {   // RNE float->bf16
    union { float f; unsigned u; } x; x.f = f;
    unsigned r = x.u + 0x7FFFu + ((x.u >> 16) & 1u);
    return (u16)(r >> 16);
}
__device__ inline void gload_lds16(const u16* g, u16* l) {
    __builtin_amdgcn_global_load_lds(
        (const __attribute__((address_space(1))) unsigned int*)g,
        (__attribute__((address_space(3))) unsigned int*)l, 16, 0, 0);
}
__device__ inline u16x8 cast8(float4 v0, float4 v1) {
    u16x8 o;
    o[0] = f2bf(v0.x); o[1] = f2bf(v0.y); o[2] = f2bf(v0.z); o[3] = f2bf(v0.w);
    o[4] = f2bf(v1.x); o[5] = f2bf(v1.y); o[6] = f2bf(v1.z); o[7] = f2bf(v1.w);
    return o;
}

// tile-index-in-batch from (mt,nt); lower-triangle cover mt>=2*nt, 20 tiles
__device__ inline int tile_tt(int mt, int nt) {
    return mt + (nt == 0 ? 0 : nt == 1 ? 6 : nt == 2 ? 10 : 12);
}

// ---------------------------------------------------------------------------
// Kernel 1 (merged, NO global memset needed):
//   blocks   0..31  -> inv_w[b] (+ out[0]=0 on block 0)
//   blocks  32..287 -> Dbf = bf16(3*max(d_hw-1,0))
//   blocks 288..319 -> bin batch b's edges by S-tile (LDS counters; block
//                      owns its 20 bins exclusively -> unconditional
//                      bincount writes, no pre-zero, no global atomics)
// ---------------------------------------------------------------------------
__global__ __launch_bounds__(256) void k_init(const float* __restrict__ edge_w,
                                              const float* __restrict__ d_hw,
                                              const int* __restrict__ esrc,
                                              const int* __restrict__ edst,
                                              float* __restrict__ inv_w,
                                              u16* __restrict__ Dbf,
                                              u32* __restrict__ bincount,
                                              uint2* __restrict__ bins,
                                              float* __restrict__ out) {
    __shared__ float red[4];
    __shared__ u32 cnt[20];
    if (blockIdx.x < 32) {
        int b = blockIdx.x;
        const float* w = edge_w + (size_t)b * Ee;
        float s = 0.f;
        for (int i = threadIdx.x; i < Ee; i += 256) s += w[i];
        for (int off = 32; off; off >>= 1) s += __shfl_down(s, off);
        int wave = threadIdx.x >> 6, lane = threadIdx.x & 63;
        if (lane == 0) red[wave] = s;
        __syncthreads();
        if (threadIdx.x == 0) {
            float t = red[0] + red[1] + red[2] + red[3];
            inv_w[b] = 1.0f / fmaxf(t, 1e-8f);
            if (b == 0) out[0] = 0.f;
        }
    } else if (blockIdx.x < 288) {
        int i = (blockIdx.x - 32) * 256 + threadIdx.x;   // 4 elems per thread
        float4 v = ((const float4*)d_hw)[i];
        ushort4 o;
        o.x = f2bf(3.f * fmaxf(v.x - 1.f, 0.f));
        o.y = f2bf(3.f * fmaxf(v.y - 1.f, 0.f));
        o.z = f2bf(3.f * fmaxf(v.z - 1.f, 0.f));
        o.w = f2bf(3.f * fmaxf(v.w - 1.f, 0.f));
        ((ushort4*)Dbf)[i] = o;
    } else {
        int b = blockIdx.x - 288;            // one block per batch
        if (threadIdx.x < 20) cnt[threadIdx.x] = 0;
        __syncthreads();
        int base = b * Ee;
        for (int i = threadIdx.x; i < Ee; i += 256) {
            int idx = base + i;
            int s = esrc[idx];
            int d = edst[idx];
            float w = edge_w[idx];
            int hi = max(s, d), lo = min(s, d);
            int tt = tile_tt(hi >> 6, lo >> 7);
            u32 pos = atomicAdd(&cnt[tt], 1u);   // LDS atomic
            if (pos < CAP)
                bins[(size_t)(b * 20 + tt) * CAP + pos] =
                    make_uint2(((u32)hi << 9) | (u32)lo, __float_as_uint(w));
        }
        __syncthreads();
        if (threadIdx.x < 20) bincount[b * 20 + threadIdx.x] = cnt[threadIdx.x];
    }
}

// ---------------------------------------------------------------------------
// Kernel 2: FULLY FUSED per-batch-panel kernel. Block = (batch bb, panel mt).
//   Phase A: G[64][512] = bf16(P_b[mt*64..+64, :]) * D   (acc in regs,
//            wave w owns G cols [w*64,+64); D streamed [512][64] via
//            global_load_lds with pre-swizzled source; A-tile reg-staged
//            f32->bf16). G -> LDS bf16 [64][512], XOR-swizzled. NO HBM G.
//   Phase B: for nt=0..mt/2: S[64][128] = G_lds * P_b[nt*128..+128,:]^T
//            (B reg-staged f32->bf16 [128][64] swz; wave owns 32x32),
//            park S in LDS f32 (+1 pad), reduce this tile's binned edges.
//   256 blocks (1/CU), 512 threads (8 waves). XCD swizzle: batch's 8
//   panels land on one XCD -> P_b, D stay L2-hot.
//   LDS: 8K A + 64K D/G + 16K B + 33K Stile = 123 KB.
// ---------------------------------------------------------------------------
__global__ __launch_bounds__(512) void k_fused(const float* __restrict__ P,
                                               const u16* __restrict__ Dbf,
                                               const u32* __restrict__ bincount,
                                               const uint2* __restrict__ bins,
                                               const float* __restrict__ inv_w,
                                               float* __restrict__ out) {
    __shared__ u16 Abuf[64 * 64];      //  8 KB phase A A-tile (swz)
    __shared__ u16 DGbuf[512 * 64];    // 64 KB phase A D-tile / phase B G [64][512]
    __shared__ u16 Bbuf[128 * 64];     // 16 KB phase B B-tile (swz)
    __shared__ float Stile[64 * 129];  // 33 KB S park (+1 pad)
    __shared__ float red[8];

    const int tid = threadIdx.x;
    const int lane = tid & 63;
    const int w = tid >> 6;                       // wave 0..7

    // XCD-chunk swizzle: blockIdx%8 = XCD (round-robin dispatch); batch's
    // 8 panels contiguous in t -> same XCD.
    int t = ((blockIdx.x & 7) << 5) + (blockIdx.x >> 3);   // 0..255
    const int bb = t >> 3;                        // batch
    const int mt = t & 7;                         // 64-row panel
    const int M0 = mt * 64;
    const float* Pb = P + (size_t)bb * Nn * Qq;

    // staging geometry (shared by all stages): thread covers 16 B
    const int srow = tid >> 3;                    // 0..63
    const int scb = tid & 7;                      // 16B col-block 0..7
    const int sxor = (scb ^ (srow & 7)) << 3;     // pre-swizzled col (shorts/f32)

    // ---------------- Phase A ----------------
    f32x4 acc[4][4] = {};
    for (int k0 = 0; k0 < Qq; k0 += 64) {
        // A-tile 64x64: reg-stage f32 -> bf16, swizzled (both sides in LDS)
        {
            const float* src = Pb + (size_t)(M0 + srow) * Qq + k0 + sxor;
            float4 v0 = *(const float4*)src;
            float4 v1 = *(const float4*)(src + 4);
            *(u16x8*)&Abuf[srow * 64 + scb * 8] = cast8(v0, v1);
        }
        // D-tile 512x64: global_load_lds, linear dest + pre-swizzled source
        #pragma unroll
        for (int p = 0; p < 8; ++p) {
            int row = p * 64 + srow;              // row&7 == srow&7
            gload_lds16(Dbf + (size_t)row * Qq + k0 + sxor,
                        DGbuf + p * 4096 + w * 512);
        }
        __syncthreads();

        #pragma unroll
        for (int kk = 0; kk < 2; ++kk) {
            bf16x8 a[4], b[4];
            #pragma unroll
            for (int mi = 0; mi < 4; ++mi) {
                int m = mi * 16 + (lane & 15);
                int cb = (kk * 4 + (lane >> 4)) ^ (m & 7);
                a[mi] = *(const bf16x8*)&Abuf[m * 64 + cb * 8];
            }
            #pragma unroll
            for (int ni = 0; ni < 4; ++ni) {
                int n = w * 64 + ni * 16 + (lane & 15);
                int cb = (kk * 4 + (lane >> 4)) ^ (n & 7);
                b[ni] = *(const bf16x8*)&DGbuf[n * 64 + cb * 8];
            }
            #pragma unroll
            for (int mi = 0; mi < 4; ++mi)
                #pragma unroll
                for (int ni = 0; ni < 4; ++ni)
                    acc[mi][ni] = __builtin_amdgcn_mfma_f32_16x16x32_bf16(
                        a[mi], b[ni], acc[mi][ni], 0, 0, 0);
        }
        __syncthreads();
    }

    // G (bf16) -> DGbuf as [64][512], 16B-block XOR swizzle (cb ^ row&7).
    // C/D layout: col=lane&15, row=(lane>>4)*4+r  [guide m89]
    #pragma unroll
    for (int mi = 0; mi < 4; ++mi) {
        #pragma unroll
        for (int ni = 0; ni < 4; ++ni) {
            #pragma unroll
            for (int r = 0; r < 4; ++r) {
                int grow = mi * 16 + (lane >> 4) * 4 + r;
                int gcol = w * 64 + ni * 16 + (lane & 15);
                int cb = (gcol >> 3) ^ (grow & 7);
                DGbuf[grow * 512 + cb * 8 + (gcol & 7)] = f2bf(acc[mi][ni][r]);
            }
        }
    }
    __syncthreads();

    // ---------------- Phase B ----------------
    float local = 0.f;
    const int wm2 = w >> 2, wn2 = w & 3;          // 2x4 waves over 64x128
    const int ntmax = mt >> 1;
    for (int nt = 0; nt <= ntmax; ++nt) {
        f32x4 acc2[2][2] = {};
        for (int k0 = 0; k0 < Qq; k0 += 64) {
            // B-tile 128x64: reg-stage f32 P rows [nt*128..+128) -> bf16, swz
            #pragma unroll
            for (int p = 0; p < 2; ++p) {
                int row = p * 64 + srow;          // row&7 == srow&7
                const float* src = Pb + (size_t)(nt * 128 + row) * Qq + k0 + sxor;
                float4 v0 = *(const float4*)src;
                float4 v1 = *(const float4*)(src + 4);
                *(u16x8*)&Bbuf[row * 64 + scb * 8] = cast8(v0, v1);
            }
            __syncthreads();

            #pragma unroll
            for (int kk = 0; kk < 2; ++kk) {
                bf16x8 a[2], b[2];
                #pragma unroll
                for (int mi = 0; mi < 2; ++mi) {
                    int m = wm2 * 32 + mi * 16 + (lane & 15);
                    int cb = ((k0 >> 3) + kk * 4 + (lane >> 4)) ^ (m & 7);
                    a[mi] = *(const bf16x8*)&DGbuf[m * 512 + cb * 8];
                }
                #pragma unroll
                for (int ni = 0; ni < 2; ++ni) {
                    int n = wn2 * 32 + ni * 16 + (lane & 15);
                    int cb = (kk * 4 + (lane >> 4)) ^ (n & 7);
                    b[ni] = *(const bf16x8*)&Bbuf[n * 64 + cb * 8];
                }
                #pragma unroll
                for (int mi = 0; mi < 2; ++mi)
                    #pragma unroll
                    for (int ni = 0; ni < 2; ++ni)
                        acc2[mi][ni] = __builtin_amdgcn_mfma_f32_16x16x32_bf16(
                            a[mi], b[ni], acc2[mi][ni], 0, 0, 0);
            }
            __syncthreads();
        }
        // park S-tile (f32, stride 129)
        #pragma unroll
        for (int mi = 0; mi < 2; ++mi)
            #pragma unroll
            for (int ni = 0; ni < 2; ++ni)
                #pragma unroll
                for (int r = 0; r < 4; ++r) {
                    int row = wm2 * 32 + mi * 16 + (lane >> 4) * 4 + r;
                    int col = wn2 * 32 + ni * 16 + (lane & 15);
                    Stile[row * 129 + col] = acc2[mi][ni][r];
                }
        __syncthreads();
        // reduce this tile's binned edges
        int bin = bb * 20 + tile_tt(mt, nt);
        int cnt = min((int)bincount[bin], CAP);
        const uint2* list = bins + (size_t)bin * CAP;
        for (int i = tid; i < cnt; i += 512) {
            uint2 e = list[i];
            int hi = (e.x >> 9) & 511, lo = e.x & 511;
            float ww = __uint_as_float(e.y);
            local += ww * Stile[(hi & 63) * 129 + (lo & 127)];
        }
        __syncthreads();   // Stile consumed before next park / Bbuf reuse
    }

    // block reduce + single atomic
    for (int off = 32; off; off >>= 1) local += __shfl_down(local, off);
    if (lane == 0) red[w] = local;
    __syncthreads();
    if (tid == 0) {
        float s = 0.f;
        #pragma unroll
        for (int i = 0; i < 8; ++i) s += red[i];
        atomicAdd(out, s * inv_w[bb] * (1.0f / Bn));
    }
}

// ---------------------------------------------------------------------------
extern "C" void kernel_launch(void* const* d_in, const int* in_sizes, int n_in,
                              void* d_out, int out_size, void* d_ws, size_t ws_size,
                              hipStream_t stream) {
    const float* P    = (const float*)d_in[0];   // [B,N,Q] f32
    const float* d_hw = (const float*)d_in[1];   // [Q,Q]   f32
    const int* esrc   = (const int*)d_in[2];     // [B,E]
    const int* edst   = (const int*)d_in[3];     // [B,E]
    const float* ew   = (const float*)d_in[4];   // [B,E]
    float* out = (float*)d_out;

    char* ws = (char*)d_ws;
    float* inv_w = (float*)ws;                           // 32 f32
    u32* bincount = (u32*)(ws + 1024);                   // 640 u32
    uint2* bins = (uint2*)(ws + 8192);                   // 640*512*8 = 2.62 MB
    u16* Dbf = (u16*)(ws + 8192 + (size_t)640 * CAP * 8);       // 0.52 MB

    k_init<<<dim3(320), dim3(256), 0, stream>>>(
        ew, d_hw, esrc, edst, inv_w, Dbf, bincount, bins, out);
    k_fused<<<dim3(256), dim3(512), 0, stream>>>(
        P, Dbf, bincount, bins, inv_w, out);
}

// Round 12
// 54.943 us; speedup vs baseline: 1.1023x; 1.1023x over previous
//
#include <hip/hip_runtime.h>

// Problem constants (match reference)
constexpr int Bn = 32;      // batch
constexpr int Nn = 512;     // logical qubits
constexpr int Qq = 512;     // physical qubits
constexpr int Ee = 4096;    // edges per batch
constexpr int Mtot = Bn * Nn;  // 16384 rows of P_flat

typedef short bf16x8 __attribute__((ext_vector_type(8)));
typedef float f32x4 __attribute__((ext_vector_type(4)));
typedef unsigned short u16;
typedef unsigned short u16x8 __attribute__((ext_vector_type(8)));

__device__ inline u16 f2bf(float f) {   // RNE float->bf16
    union { float f; unsigned u; } x; x.f = f;
    unsigned r = x.u + 0x7FFFu + ((x.u >> 16) & 1u);
    return (u16)(r >> 16);
}
__device__ inline float bf2f(u16 h) {
    union { unsigned u; float f; } x; x.u = ((unsigned)h) << 16;
    return x.f;
}
__device__ inline void gload_lds16(const u16* g, u16* l) {
    __builtin_amdgcn_global_load_lds(
        (const __attribute__((address_space(1))) unsigned int*)g,
        (__attribute__((address_space(3))) unsigned int*)l, 16, 0, 0);
}
__device__ inline u16x8 cast8(float4 v0, float4 v1) {
    u16x8 o;
    o[0] = f2bf(v0.x); o[1] = f2bf(v0.y); o[2] = f2bf(v0.z); o[3] = f2bf(v0.w);
    o[4] = f2bf(v1.x); o[5] = f2bf(v1.y); o[6] = f2bf(v1.z); o[7] = f2bf(v1.w);
    return o;
}

// ---------------------------------------------------------------------------
// Kernel 1 (merged): blocks 0..31  -> inv_w[b] (+ out[0]=0 on block 0)
//                    blocks 32..287 -> Dbf = bf16(3*max(d_hw-1,0))
// ---------------------------------------------------------------------------
__global__ __launch_bounds__(256) void k_init(const float* __restrict__ edge_w,
                                              const float* __restrict__ d_hw,
                                              float* __restrict__ inv_w,
                                              u16* __restrict__ Dbf,
                                              float* __restrict__ out) {
    if (blockIdx.x < 32) {
        int b = blockIdx.x;
        const float* w = edge_w + (size_t)b * Ee;
        float s = 0.f;
        for (int i = threadIdx.x; i < Ee; i += 256) s += w[i];
        for (int off = 32; off; off >>= 1) s += __shfl_down(s, off);
        __shared__ float red[4];
        int wave = threadIdx.x >> 6, lane = threadIdx.x & 63;
        if (lane == 0) red[wave] = s;
        __syncthreads();
        if (threadIdx.x == 0) {
            float t = red[0] + red[1] + red[2] + red[3];
            inv_w[b] = 1.0f / fmaxf(t, 1e-8f);
            if (b == 0) out[0] = 0.f;
        }
    } else {
        int i = (blockIdx.x - 32) * 256 + threadIdx.x;   // 4 elems per thread
        float4 v = ((const float4*)d_hw)[i];
        ushort4 o;
        o.x = f2bf(3.f * fmaxf(v.x - 1.f, 0.f));
        o.y = f2bf(3.f * fmaxf(v.y - 1.f, 0.f));
        o.z = f2bf(3.f * fmaxf(v.z - 1.f, 0.f));
        o.w = f2bf(3.f * fmaxf(v.w - 1.f, 0.f));
        ((ushort4*)Dbf)[i] = o;
    }
}

// ---------------------------------------------------------------------------
// Kernel 2: fused cast+GEMM1:  G = bf16(P) * D^T  (D symmetric), 2-PHASE
//   pipeline (T3 minimum): double-buffered LDS, stage tile t+1 BEFORE the
//   MFMA of tile t, ONE barrier per K-step. BM=64, BN=128, BK=32, 4 waves.
//   A reg-staged f32->bf16 (ds_write after MFMA so loads land under compute);
//   B via global_load_lds. N0==0 blocks publish bf16 A to Pbf.
//   1D grid 1024 + bijective XCD-chunk swizzle.
// ---------------------------------------------------------------------------
__global__ __launch_bounds__(256) void k_gemm1(const float* __restrict__ P,
                                               const u16* __restrict__ Dbf,
                                               u16* __restrict__ Pbf,
                                               u16* __restrict__ G) {
    __shared__ u16 As[2][64 * 32];    // 2 x 4 KB
    __shared__ u16 Bs[2][128 * 32];   // 2 x 8 KB
    const int tid = threadIdx.x;
    const int lane = tid & 63;
    const int wave = tid >> 6;
    const int wm = wave >> 1, wn = wave & 1;

    int t0 = (blockIdx.x & 7) * 128 + (blockIdx.x >> 3);
    int xt = t0 & 3, yt = t0 >> 2;      // consecutive share yt (A-panel)
    const int M0 = yt * 64, N0 = xt * 128;

    const int srow = tid >> 2;            // 0..63
    const int scol = (tid & 3) * 8;

    const float* gA = P + (size_t)(M0 + srow) * Qq + scol;
    const u16* gB = Dbf + (size_t)(N0 + srow) * Qq + scol;
    u16* pOut = Pbf + (size_t)(M0 + srow) * Qq + scol;

    // prologue: stage tile 0
    gload_lds16(gB, &Bs[0][wave * 512]);
    gload_lds16(gB + (size_t)64 * Qq, &Bs[0][2048 + wave * 512]);
    {
        float4 v0 = *(const float4*)gA;
        float4 v1 = *(const float4*)(gA + 4);
        u16x8 o = cast8(v0, v1);
        *(u16x8*)&As[0][srow * 32 + scol] = o;
        if (N0 == 0) *(u16x8*)pOut = o;
    }
    __syncthreads();

    f32x4 acc[2][4] = {};

    for (int t = 0; t < 16; ++t) {
        const int cur = t & 1;
        const int k1 = (t + 1) * 32;
        float4 v0, v1;
        if (t < 15) {
            // issue next tile's loads: they fly during this tile's MFMAs
            gload_lds16(gB + k1, &Bs[cur ^ 1][wave * 512]);
            gload_lds16(gB + (size_t)64 * Qq + k1, &Bs[cur ^ 1][2048 + wave * 512]);
            v0 = *(const float4*)(gA + k1);
            v1 = *(const float4*)(gA + k1 + 4);
        }

        bf16x8 a[2], b[4];
        #pragma unroll
        for (int mi = 0; mi < 2; ++mi)
            a[mi] = *(const bf16x8*)&As[cur][(wm * 32 + mi * 16 + (lane & 15)) * 32 + (lane >> 4) * 8];
        #pragma unroll
        for (int ni = 0; ni < 4; ++ni)
            b[ni] = *(const bf16x8*)&Bs[cur][(wn * 64 + ni * 16 + (lane & 15)) * 32 + (lane >> 4) * 8];
        #pragma unroll
        for (int mi = 0; mi < 2; ++mi)
            #pragma unroll
            for (int ni = 0; ni < 4; ++ni)
                acc[mi][ni] = __builtin_amdgcn_mfma_f32_16x16x32_bf16(a[mi], b[ni], acc[mi][ni], 0, 0, 0);

        if (t < 15) {
            u16x8 o = cast8(v0, v1);          // loads had MFMA phase to land
            *(u16x8*)&As[cur ^ 1][srow * 32 + scol] = o;
            if (N0 == 0) *(u16x8*)(pOut + k1) = o;
        }
        __syncthreads();   // single barrier per K-step
    }

    // epilogue: C/D layout col=lane&15, row=(lane>>4)*4+r  [guide m89]
    const int r0 = (lane >> 4) * 4;
    const int c = lane & 15;
    #pragma unroll
    for (int mi = 0; mi < 2; ++mi) {
        #pragma unroll
        for (int ni = 0; ni < 4; ++ni) {
            int row = M0 + wm * 32 + mi * 16 + r0;
            int col = N0 + wn * 64 + ni * 16 + c;
            #pragma unroll
            for (int r = 0; r < 4; ++r)
                G[(size_t)(row + r) * Qq + col] = f2bf(acc[mi][ni][r]);
        }
    }
}

// ---------------------------------------------------------------------------
// Kernel 3: GEMM2  S_b = G_b * P_b^T  (symmetric -> lower-triangle tiles),
//   2-PHASE pipeline, both operands via global_load_lds. 640 blocks,
//   XCD-chunk swizzle.
// ---------------------------------------------------------------------------
__global__ __launch_bounds__(256) void k_gemm2(const u16* __restrict__ A,
                                               const u16* __restrict__ Bt,
                                               u16* __restrict__ C) {
    __shared__ u16 As[2][64 * 32];    // 2 x 4 KB
    __shared__ u16 Bs[2][128 * 32];   // 2 x 8 KB
    const int tid = threadIdx.x;
    const int lane = tid & 63;
    const int wave = tid >> 6;
    const int wm = wave >> 1, wn = wave & 1;

    int t0 = (blockIdx.x & 7) * 80 + (blockIdx.x >> 3);   // nwg=640=8*80
    int bb = t0 / 20, tt = t0 % 20;
    int nt = (tt < 8) ? 0 : (tt < 14) ? 1 : (tt < 18) ? 2 : 3;
    int mt = (tt < 8) ? tt : (tt < 14) ? tt - 6 : (tt < 18) ? tt - 10 : tt - 12;
    const int M0 = bb * 512 + mt * 64, N0 = nt * 128;
    const u16* Bbase = Bt + (size_t)bb * Nn * Qq;

    const int srow = tid >> 2;
    const int scol = (tid & 3) * 8;

    const u16* gA = A + (size_t)(M0 + srow) * Qq + scol;
    const u16* gB = Bbase + (size_t)(N0 + srow) * Qq + scol;

    // prologue: stage tile 0
    gload_lds16(gA, &As[0][wave * 512]);
    gload_lds16(gB, &Bs[0][wave * 512]);
    gload_lds16(gB + (size_t)64 * Qq, &Bs[0][2048 + wave * 512]);
    __syncthreads();

    f32x4 acc[2][4] = {};

    for (int t = 0; t < 16; ++t) {
        const int cur = t & 1;
        const int k1 = (t + 1) * 32;
        if (t < 15) {
            gload_lds16(gA + k1, &As[cur ^ 1][wave * 512]);
            gload_lds16(gB + k1, &Bs[cur ^ 1][wave * 512]);
            gload_lds16(gB + (size_t)64 * Qq + k1, &Bs[cur ^ 1][2048 + wave * 512]);
        }

        bf16x8 a[2], b[4];
        #pragma unroll
        for (int mi = 0; mi < 2; ++mi)
            a[mi] = *(const bf16x8*)&As[cur][(wm * 32 + mi * 16 + (lane & 15)) * 32 + (lane >> 4) * 8];
        #pragma unroll
        for (int ni = 0; ni < 4; ++ni)
            b[ni] = *(const bf16x8*)&Bs[cur][(wn * 64 + ni * 16 + (lane & 15)) * 32 + (lane >> 4) * 8];
        #pragma unroll
        for (int mi = 0; mi < 2; ++mi)
            #pragma unroll
            for (int ni = 0; ni < 4; ++ni)
                acc[mi][ni] = __builtin_amdgcn_mfma_f32_16x16x32_bf16(a[mi], b[ni], acc[mi][ni], 0, 0, 0);
        __syncthreads();   // single barrier per K-step
    }

    const int r0 = (lane >> 4) * 4;
    const int c = lane & 15;
    u16* Crow = C + (size_t)M0 * Qq;
    #pragma unroll
    for (int mi = 0; mi < 2; ++mi) {
        #pragma unroll
        for (int ni = 0; ni < 4; ++ni) {
            int row = wm * 32 + mi * 16 + r0;
            int col = N0 + wn * 64 + ni * 16 + c;
            #pragma unroll
            for (int r = 0; r < 4; ++r)
                Crow[(size_t)(row + r) * Qq + col] = f2bf(acc[mi][ni][r]);
        }
    }
}

// ---------------------------------------------------------------------------
// Kernel 4: out += sum_e w_e * S[b, max(s,d), min(s,d)] * inv_w[b] / B
// ---------------------------------------------------------------------------
__global__ __launch_bounds__(256) void k_lookup(const u16* __restrict__ S,
                                                const int* __restrict__ esrc,
                                                const int* __restrict__ edst,
                                                const float* __restrict__ ew,
                                                const float* __restrict__ inv_w,
                                                float* __restrict__ out) {
    int idx = blockIdx.x * 256 + threadIdx.x;   // 0 .. B*E-1
    int b = idx >> 12;                          // / 4096
    int s = esrc[idx];
    int d = edst[idx];
    int hi = max(s, d), lo = min(s, d);
    float w = ew[idx] * inv_w[b];
    float val = bf2f(S[((size_t)b << 18) + ((size_t)hi << 9) + (size_t)lo]);
    float local = w * val;
    for (int off = 32; off; off >>= 1) local += __shfl_down(local, off);
    __shared__ float red[4];
    int wave = threadIdx.x >> 6, lane = threadIdx.x & 63;
    if (lane == 0) red[wave] = local;
    __syncthreads();
    if (threadIdx.x == 0)
        atomicAdd(out, (red[0] + red[1] + red[2] + red[3]) * (1.0f / Bn));
}

// ---------------------------------------------------------------------------
extern "C" void kernel_launch(void* const* d_in, const int* in_sizes, int n_in,
                              void* d_out, int out_size, void* d_ws, size_t ws_size,
                              hipStream_t stream) {
    const float* P    = (const float*)d_in[0];   // [B,N,Q] f32
    const float* d_hw = (const float*)d_in[1];   // [Q,Q]   f32
    const int* esrc   = (const int*)d_in[2];     // [B,E]
    const int* edst   = (const int*)d_in[3];     // [B,E]
    const float* ew   = (const float*)d_in[4];   // [B,E]
    float* out = (float*)d_out;

    char* ws = (char*)d_ws;
    float* inv_w = (float*)ws;                          // 32 f32 (1 KB reserved)
    u16* Pbf = (u16*)(ws + 1024);                       // [Mtot][512] bf16, 16.78 MB
    u16* Dbf = Pbf + (size_t)Mtot * Qq;                 // [512][512]  bf16, 0.52 MB
    u16* G   = Dbf + (size_t)Qq * Qq;                   // [Mtot][512] bf16, 16.78 MB
    u16* S   = G + (size_t)Mtot * Qq;                   // [B][512][512] bf16, 16.78 MB

    k_init<<<dim3(288), dim3(256), 0, stream>>>(ew, d_hw, inv_w, Dbf, out);
    k_gemm1<<<dim3(1024), dim3(256), 0, stream>>>(P, Dbf, Pbf, G);
    k_gemm2<<<dim3(640), dim3(256), 0, stream>>>(G, Pbf, S);
    k_lookup<<<dim3((Bn * Ee) / 256), dim3(256), 0, stream>>>(
        S, esrc, edst, ew, inv_w, out);
}

// Round 13
// 54.002 us; speedup vs baseline: 1.1214x; 1.0174x over previous
//
#include <hip/hip_runtime.h>

// Problem constants (match reference)
constexpr int Bn = 32;      // batch
constexpr int Nn = 512;     // logical qubits
constexpr int Qq = 512;     // physical qubits
constexpr int Ee = 4096;    // edges per batch
constexpr int Mtot = Bn * Nn;  // 16384 rows of P_flat

typedef short bf16x8 __attribute__((ext_vector_type(8)));
typedef float f32x4 __attribute__((ext_vector_type(4)));
typedef unsigned short u16;
typedef unsigned short u16x8 __attribute__((ext_vector_type(8)));

__device__ inline u16 f2bf(float f) {   // RNE float->bf16
    union { float f; unsigned u; } x; x.f = f;
    unsigned r = x.u + 0x7FFFu + ((x.u >> 16) & 1u);
    return (u16)(r >> 16);
}
__device__ inline float bf2f(u16 h) {
    union { unsigned u; float f; } x; x.u = ((unsigned)h) << 16;
    return x.f;
}
__device__ inline void gload_lds16(const u16* g, u16* l) {
    __builtin_amdgcn_global_load_lds(
        (const __attribute__((address_space(1))) unsigned int*)g,
        (__attribute__((address_space(3))) unsigned int*)l, 16, 0, 0);
}
__device__ inline u16x8 cast8(float4 v0, float4 v1) {
    u16x8 o;
    o[0] = f2bf(v0.x); o[1] = f2bf(v0.y); o[2] = f2bf(v0.z); o[3] = f2bf(v0.w);
    o[4] = f2bf(v1.x); o[5] = f2bf(v1.y); o[6] = f2bf(v1.z); o[7] = f2bf(v1.w);
    return o;
}

// ---------------------------------------------------------------------------
// Kernel 1 (merged): blocks 0..31  -> inv_w[b] (+ out[0]=0 on block 0)
//                    blocks 32..287 -> Dbf = bf16(3*max(d_hw-1,0))
// ---------------------------------------------------------------------------
__global__ __launch_bounds__(256) void k_init(const float* __restrict__ edge_w,
                                              const float* __restrict__ d_hw,
                                              float* __restrict__ inv_w,
                                              u16* __restrict__ Dbf,
                                              float* __restrict__ out) {
    if (blockIdx.x < 32) {
        int b = blockIdx.x;
        const float* w = edge_w + (size_t)b * Ee;
        float s = 0.f;
        for (int i = threadIdx.x; i < Ee; i += 256) s += w[i];
        for (int off = 32; off; off >>= 1) s += __shfl_down(s, off);
        __shared__ float red[4];
        int wave = threadIdx.x >> 6, lane = threadIdx.x & 63;
        if (lane == 0) red[wave] = s;
        __syncthreads();
        if (threadIdx.x == 0) {
            float t = red[0] + red[1] + red[2] + red[3];
            inv_w[b] = 1.0f / fmaxf(t, 1e-8f);
            if (b == 0) out[0] = 0.f;
        }
    } else {
        int i = (blockIdx.x - 32) * 256 + threadIdx.x;   // 4 elems per thread
        float4 v = ((const float4*)d_hw)[i];
        ushort4 o;
        o.x = f2bf(3.f * fmaxf(v.x - 1.f, 0.f));
        o.y = f2bf(3.f * fmaxf(v.y - 1.f, 0.f));
        o.z = f2bf(3.f * fmaxf(v.z - 1.f, 0.f));
        o.w = f2bf(3.f * fmaxf(v.w - 1.f, 0.f));
        ((ushort4*)Dbf)[i] = o;
    }
}

// ---------------------------------------------------------------------------
// Kernel 2: fused cast+GEMM1  G = bf16(P) * D^T, T3/T4 pipeline:
//   3-buffer LDS rotation, depth-2 prefetch, RAW s_barrier (no vmcnt drain).
//   Correctness of B(t) before compute(t): B(t+?) gloads are issued BEFORE
//   the A(t+?) reg-loads of the same tile, so the compiler's vmcnt wait for
//   A(t+1) (before its cast/ds_write, FIFO) retires all older vmem incl.
//   B(t). barrier1 (with lgkmcnt(0)) publishes the A ds_write; barrier2
//   (post-compute) protects buffer (t+2)%3 == (t-1)%3 from the next gload.
//   BM=64, BN=128, BK=32, 4 waves 2x2, acc[2][4]. N0==0 publishes Pbf.
// ---------------------------------------------------------------------------
__global__ __launch_bounds__(256) void k_gemm1(const float* __restrict__ P,
                                               const u16* __restrict__ Dbf,
                                               u16* __restrict__ Pbf,
                                               u16* __restrict__ G) {
    __shared__ u16 As[3][64 * 32];     // 3 x 4 KB
    __shared__ u16 Bs[3][128 * 32];    // 3 x 8 KB
    const int tid = threadIdx.x;
    const int lane = tid & 63;
    const int wave = tid >> 6;
    const int wm = wave >> 1, wn = wave & 1;

    int t0 = (blockIdx.x & 7) * 128 + (blockIdx.x >> 3);   // XCD swizzle
    int xt = t0 & 3, yt = t0 >> 2;
    const int M0 = yt * 64, N0 = xt * 128;

    const int srow = tid >> 2;            // 0..63
    const int scol = (tid & 3) * 8;

    const float* gA = P + (size_t)(M0 + srow) * Qq + scol;
    const u16* gB = Dbf + (size_t)(N0 + srow) * Qq + scol;
    u16* pOut = Pbf + (size_t)(M0 + srow) * Qq + scol;

    float4 vA0, vA1;
    // prologue: tile 0 (B gloads first, then A regs), write A(0); tile 1 issue
    gload_lds16(gB, &Bs[0][wave * 512]);
    gload_lds16(gB + (size_t)64 * Qq, &Bs[0][2048 + wave * 512]);
    vA0 = *(const float4*)gA; vA1 = *(const float4*)(gA + 4);
    {
        u16x8 o = cast8(vA0, vA1);                 // compiler waits A(0) here
        *(u16x8*)&As[0][srow * 32 + scol] = o;
        if (N0 == 0) *(u16x8*)pOut = o;
    }
    gload_lds16(gB + 32, &Bs[1][wave * 512]);
    gload_lds16(gB + (size_t)64 * Qq + 32, &Bs[1][2048 + wave * 512]);
    vA0 = *(const float4*)(gA + 32); vA1 = *(const float4*)(gA + 36);

    f32x4 acc[2][4] = {};

    #pragma unroll
    for (int t = 0; t < 15; ++t) {
        const int wb = (t + 1) % 3, pb = (t + 2) % 3, cb = t % 3;
        {
            u16x8 o = cast8(vA0, vA1);             // compiler waits A(t+1):
            *(u16x8*)&As[wb][srow * 32 + scol] = o; // FIFO-retires B(t) too
            if (N0 == 0) *(u16x8*)(pOut + (t + 1) * 32) = o;
        }
        if (t < 14) {
            const int k2 = (t + 2) * 32;
            gload_lds16(gB + k2, &Bs[pb][wave * 512]);
            gload_lds16(gB + (size_t)64 * Qq + k2, &Bs[pb][2048 + wave * 512]);
            vA0 = *(const float4*)(gA + k2); vA1 = *(const float4*)(gA + k2 + 4);
        }
        asm volatile("s_waitcnt lgkmcnt(0)" ::: "memory");
        __builtin_amdgcn_s_barrier();              // NO vmcnt drain
        __builtin_amdgcn_sched_barrier(0);

        bf16x8 a[2], b[4];
        #pragma unroll
        for (int mi = 0; mi < 2; ++mi)
            a[mi] = *(const bf16x8*)&As[cb][(wm * 32 + mi * 16 + (lane & 15)) * 32 + (lane >> 4) * 8];
        #pragma unroll
        for (int ni = 0; ni < 4; ++ni)
            b[ni] = *(const bf16x8*)&Bs[cb][(wn * 64 + ni * 16 + (lane & 15)) * 32 + (lane >> 4) * 8];
        #pragma unroll
        for (int mi = 0; mi < 2; ++mi)
            #pragma unroll
            for (int ni = 0; ni < 4; ++ni)
                acc[mi][ni] = __builtin_amdgcn_mfma_f32_16x16x32_bf16(a[mi], b[ni], acc[mi][ni], 0, 0, 0);

        __builtin_amdgcn_sched_barrier(0);
        __builtin_amdgcn_s_barrier();              // protect (t-1)%3 buffer
    }
    // peel t=15: buffers ready & visible (written before barrier1(14))
    {
        bf16x8 a[2], b[4];
        #pragma unroll
        for (int mi = 0; mi < 2; ++mi)
            a[mi] = *(const bf16x8*)&As[0][(wm * 32 + mi * 16 + (lane & 15)) * 32 + (lane >> 4) * 8];
        #pragma unroll
        for (int ni = 0; ni < 4; ++ni)
            b[ni] = *(const bf16x8*)&Bs[0][(wn * 64 + ni * 16 + (lane & 15)) * 32 + (lane >> 4) * 8];
        #pragma unroll
        for (int mi = 0; mi < 2; ++mi)
            #pragma unroll
            for (int ni = 0; ni < 4; ++ni)
                acc[mi][ni] = __builtin_amdgcn_mfma_f32_16x16x32_bf16(a[mi], b[ni], acc[mi][ni], 0, 0, 0);
    }

    // epilogue: C/D layout col=lane&15, row=(lane>>4)*4+r  [guide m89]
    const int r0 = (lane >> 4) * 4;
    const int c = lane & 15;
    #pragma unroll
    for (int mi = 0; mi < 2; ++mi) {
        #pragma unroll
        for (int ni = 0; ni < 4; ++ni) {
            int row = M0 + wm * 32 + mi * 16 + r0;
            int col = N0 + wn * 64 + ni * 16 + c;
            #pragma unroll
            for (int r = 0; r < 4; ++r)
                G[(size_t)(row + r) * Qq + col] = f2bf(acc[mi][ni][r]);
        }
    }
}

// ---------------------------------------------------------------------------
// Kernel 3: GEMM2  S_b = G_b * P_b^T (lower-triangle tiles), T3/T4 pipeline:
//   all-gload staging, explicit counted vmcnt(3) per iter (retire tile t+1,
//   keep tile t+2's 3 loads in flight). Raw barriers as in gemm1.
// ---------------------------------------------------------------------------
__global__ __launch_bounds__(256) void k_gemm2(const u16* __restrict__ A,
                                               const u16* __restrict__ Bt,
                                               u16* __restrict__ C) {
    __shared__ u16 As[3][64 * 32];
    __shared__ u16 Bs[3][128 * 32];
    const int tid = threadIdx.x;
    const int lane = tid & 63;
    const int wave = tid >> 6;
    const int wm = wave >> 1, wn = wave & 1;

    int t0 = (blockIdx.x & 7) * 80 + (blockIdx.x >> 3);   // nwg=640=8*80
    int bb = t0 / 20, tt = t0 % 20;
    int nt = (tt < 8) ? 0 : (tt < 14) ? 1 : (tt < 18) ? 2 : 3;
    int mt = (tt < 8) ? tt : (tt < 14) ? tt - 6 : (tt < 18) ? tt - 10 : tt - 12;
    const int M0 = bb * 512 + mt * 64, N0 = nt * 128;
    const u16* Bbase = Bt + (size_t)bb * Nn * Qq;

    const int srow = tid >> 2;
    const int scol = (tid & 3) * 8;

    const u16* gA = A + (size_t)(M0 + srow) * Qq + scol;
    const u16* gB = Bbase + (size_t)(N0 + srow) * Qq + scol;

    // prologue: tiles 0 and 1 (3 gloads each)
    gload_lds16(gA, &As[0][wave * 512]);
    gload_lds16(gB, &Bs[0][wave * 512]);
    gload_lds16(gB + (size_t)64 * Qq, &Bs[0][2048 + wave * 512]);
    gload_lds16(gA + 32, &As[1][wave * 512]);
    gload_lds16(gB + 32, &Bs[1][wave * 512]);
    gload_lds16(gB + (size_t)64 * Qq + 32, &Bs[1][2048 + wave * 512]);

    f32x4 acc[2][4] = {};

    #pragma unroll
    for (int t = 0; t < 15; ++t) {
        const int pb = (t + 2) % 3, cb = t % 3;
        if (t < 14) {
            const int k2 = (t + 2) * 32;
            gload_lds16(gA + k2, &As[pb][wave * 512]);
            gload_lds16(gB + k2, &Bs[pb][wave * 512]);
            gload_lds16(gB + (size_t)64 * Qq + k2, &Bs[pb][2048 + wave * 512]);
        }
        asm volatile("s_waitcnt vmcnt(3)" ::: "memory");  // tile t+1 landed;
        __builtin_amdgcn_s_barrier();                     // t+2 stays in flight
        __builtin_amdgcn_sched_barrier(0);

        bf16x8 a[2], b[4];
        #pragma unroll
        for (int mi = 0; mi < 2; ++mi)
            a[mi] = *(const bf16x8*)&As[cb][(wm * 32 + mi * 16 + (lane & 15)) * 32 + (lane >> 4) * 8];
        #pragma unroll
        for (int ni = 0; ni < 4; ++ni)
            b[ni] = *(const bf16x8*)&Bs[cb][(wn * 64 + ni * 16 + (lane & 15)) * 32 + (lane >> 4) * 8];
        #pragma unroll
        for (int mi = 0; mi < 2; ++mi)
            #pragma unroll
            for (int ni = 0; ni < 4; ++ni)
                acc[mi][ni] = __builtin_amdgcn_mfma_f32_16x16x32_bf16(a[mi], b[ni], acc[mi][ni], 0, 0, 0);

        __builtin_amdgcn_sched_barrier(0);
        __builtin_amdgcn_s_barrier();
    }
    // peel t=15
    asm volatile("s_waitcnt vmcnt(0)" ::: "memory");
    __builtin_amdgcn_s_barrier();
    __builtin_amdgcn_sched_barrier(0);
    {
        bf16x8 a[2], b[4];
        #pragma unroll
        for (int mi = 0; mi < 2; ++mi)
            a[mi] = *(const bf16x8*)&As[0][(wm * 32 + mi * 16 + (lane & 15)) * 32 + (lane >> 4) * 8];
        #pragma unroll
        for (int ni = 0; ni < 4; ++ni)
            b[ni] = *(const bf16x8*)&Bs[0][(wn * 64 + ni * 16 + (lane & 15)) * 32 + (lane >> 4) * 8];
        #pragma unroll
        for (int mi = 0; mi < 2; ++mi)
            #pragma unroll
            for (int ni = 0; ni < 4; ++ni)
                acc[mi][ni] = __builtin_amdgcn_mfma_f32_16x16x32_bf16(a[mi], b[ni], acc[mi][ni], 0, 0, 0);
    }

    const int r0 = (lane >> 4) * 4;
    const int c = lane & 15;
    u16* Crow = C + (size_t)M0 * Qq;
    #pragma unroll
    for (int mi = 0; mi < 2; ++mi) {
        #pragma unroll
        for (int ni = 0; ni < 4; ++ni) {
            int row = wm * 32 + mi * 16 + r0;
            int col = N0 + wn * 64 + ni * 16 + c;
            #pragma unroll
            for (int r = 0; r < 4; ++r)
                Crow[(size_t)(row + r) * Qq + col] = f2bf(acc[mi][ni][r]);
        }
    }
}

// ---------------------------------------------------------------------------
// Kernel 4: out += sum_e w_e * S[b, max(s,d), min(s,d)] * inv_w[b] / B
// ---------------------------------------------------------------------------
__global__ __launch_bounds__(256) void k_lookup(const u16* __restrict__ S,
                                                const int* __restrict__ esrc,
                                                const int* __restrict__ edst,
                                                const float* __restrict__ ew,
                                                const float* __restrict__ inv_w,
                                                float* __restrict__ out) {
    int idx = blockIdx.x * 256 + threadIdx.x;   // 0 .. B*E-1
    int b = idx >> 12;                          // / 4096
    int s = esrc[idx];
    int d = edst[idx];
    int hi = max(s, d), lo = min(s, d);
    float w = ew[idx] * inv_w[b];
    float val = bf2f(S[((size_t)b << 18) + ((size_t)hi << 9) + (size_t)lo]);
    float local = w * val;
    for (int off = 32; off; off >>= 1) local += __shfl_down(local, off);
    __shared__ float red[4];
    int wave = threadIdx.x >> 6, lane = threadIdx.x & 63;
    if (lane == 0) red[wave] = local;
    __syncthreads();
    if (threadIdx.x == 0)
        atomicAdd(out, (red[0] + red[1] + red[2] + red[3]) * (1.0f / Bn));
}

// ---------------------------------------------------------------------------
extern "C" void kernel_launch(void* const* d_in, const int* in_sizes, int n_in,
                              void* d_out, int out_size, void* d_ws, size_t ws_size,
                              hipStream_t stream) {
    const float* P    = (const float*)d_in[0];   // [B,N,Q] f32
    const float* d_hw = (const float*)d_in[1];   // [Q,Q]   f32
    const int* esrc   = (const int*)d_in[2];     // [B,E]
    const int* edst   = (const int*)d_in[3];     // [B,E]
    const float* ew   = (const float*)d_in[4];   // [B,E]
    float* out = (float*)d_out;

    char* ws = (char*)d_ws;
    float* inv_w = (float*)ws;                          // 32 f32 (1 KB reserved)
    u16* Pbf = (u16*)(ws + 1024);                       // [Mtot][512] bf16, 16.78 MB
    u16* Dbf = Pbf + (size_t)Mtot * Qq;                 // [512][512]  bf16, 0.52 MB
    u16* G   = Dbf + (size_t)Qq * Qq;                   // [Mtot][512] bf16, 16.78 MB
    u16* S   = G + (size_t)Mtot * Qq;                   // [B][512][512] bf16, 16.78 MB

    k_init<<<dim3(288), dim3(256), 0, stream>>>(ew, d_hw, inv_w, Dbf, out);
    k_gemm1<<<dim3(1024), dim3(256), 0, stream>>>(P, Dbf, Pbf, G);
    k_gemm2<<<dim3(640), dim3(256), 0, stream>>>(G, Pbf, S);
    k_lookup<<<dim3((Bn * Ee) / 256), dim3(256), 0, stream>>>(
        S, esrc, edst, ew, inv_w, out);
}